// Round 1
// 14774.525 us; speedup vs baseline: 2.2417x; 2.2417x over previous
//
#include <hip/hip_runtime.h>
#include <hip/hip_bf16.h>

typedef __attribute__((ext_vector_type(8))) short short8;
typedef __attribute__((ext_vector_type(4))) float float4v;

__device__ __forceinline__ float bf2f(short b) {
    unsigned u = ((unsigned)(unsigned short)b) << 16;
    union { unsigned u; float f; } c; c.u = u; return c.f;
}
__device__ __forceinline__ short f2bf(float f) {
    union { float f; unsigned u; } c; c.f = f;
    unsigned r = 0x7FFFu + ((c.u >> 16) & 1u);
    return (short)((c.u + r) >> 16);
}
// dtype-dispatched scalar load (flag: false=bf16, true=fp32)
__device__ __forceinline__ float ldf(const void* p, size_t i, bool f32) {
    return f32 ? ((const float*)p)[i] : bf2f(((const short*)p)[i]);
}
// dtype-dispatched 8-element MFMA fragment load (rounds fp32 -> bf16)
__device__ __forceinline__ short8 frag8(const void* p, size_t i, bool f32) {
    short8 r;
    if (f32) {
        const float* q = (const float*)p + i;
#pragma unroll
        for (int j = 0; j < 8; j++) r[j] = f2bf(q[j]);
    } else {
        r = *(const short8*)((const short*)p + i);
    }
    return r;
}

// async global->LDS DMA, 16B per lane; LDS dest is wave-uniform base + lane*16
__device__ __forceinline__ void gll16(const short* gp, short* lp) {
    __builtin_amdgcn_global_load_lds(
        (__attribute__((address_space(1))) void*)gp,
        (__attribute__((address_space(3))) void*)lp, 16, 0, 0);
}

// ---------------- dtype detector: 0 = bf16, 1 = fp32 ----------------
__global__ void detect_dtype(const unsigned short* __restrict__ in, unsigned* __restrict__ flag)
{
    int t = threadIdx.x;  // 64 threads
    int sane = 0;
    for (int i = t; i < 256; i += 64) {
        unsigned e = (in[i] >> 7) & 0xFF;
        sane += (e >= 0x70 && e <= 0x8A) ? 1 : 0;
    }
#pragma unroll
    for (int o = 32; o > 0; o >>= 1) sane += __shfl_down(sane, o);
    if (t == 0) *flag = (sane >= 200) ? 0u : 1u;
}

// ---------------- init scratch (h ping-pong hi/lo planes + counters) ----------------
__global__ void init_scratch(short* __restrict__ hb, unsigned* __restrict__ cnt)
{
    int i = blockIdx.x * 256 + threadIdx.x;
    if (i < 4 * 65536) hb[i] = 0;
    if (i < 512) cnt[i] = 0;
}

// ---------------- C = A @ B^T + bias, bf16 MFMA, optional fp32 hi/lo split --------
__global__ __launch_bounds__(256, 1) void gemm_bt(
    const void* __restrict__ A, const void* __restrict__ B,
    const void* __restrict__ bias, void* __restrict__ outbase, size_t coff,
    const unsigned* __restrict__ flag, int M, int N, int K)
{
    const bool f32 = flag && (flag[0] != 0u);
    __shared__ short Ah[128][72], Bh[128][72];
    __shared__ short Al[128][72], Bl[128][72];
    const int tid  = threadIdx.x;
    const int wid  = tid >> 6;
    const int lane = tid & 63;
    const int ln = lane & 15, q = lane >> 4;
    const int bm = blockIdx.x * 128, bn = blockIdx.y * 128;
    const int wm = (wid & 1) * 64, wn = (wid >> 1) * 64;

    float4v acc[4][4];
#pragma unroll
    for (int i = 0; i < 4; i++)
#pragma unroll
        for (int j = 0; j < 4; j++) acc[i][j] = (float4v){0.f, 0.f, 0.f, 0.f};

    for (int k0 = 0; k0 < K; k0 += 64) {
#pragma unroll
        for (int c = 0; c < 4; c++) {
            int chunk = tid + c * 256;
            int row = chunk >> 3;
            int kq  = (chunk & 7) * 8;
            size_t ga = (size_t)(bm + row) * K + k0 + kq;
            size_t gb = (size_t)(bn + row) * K + k0 + kq;
            if (f32) {
                const float* Af = (const float*)A;
                const float* Bf = (const float*)B;
#pragma unroll
                for (int j = 0; j < 8; j++) {
                    float av = Af[ga + j], bv = Bf[gb + j];
                    short ah = f2bf(av), bh = f2bf(bv);
                    Ah[row][kq + j] = ah; Al[row][kq + j] = f2bf(av - bf2f(ah));
                    Bh[row][kq + j] = bh; Bl[row][kq + j] = f2bf(bv - bf2f(bh));
                }
            } else {
                *(short8*)&Ah[row][kq] = *(const short8*)((const short*)A + ga);
                *(short8*)&Bh[row][kq] = *(const short8*)((const short*)B + gb);
            }
        }
        __syncthreads();
#pragma unroll
        for (int kt = 0; kt < 2; kt++) {
            short8 avh[4], bvh[4];
#pragma unroll
            for (int i = 0; i < 4; i++) avh[i] = *(const short8*)&Ah[wm + i * 16 + ln][kt * 32 + q * 8];
#pragma unroll
            for (int j = 0; j < 4; j++) bvh[j] = *(const short8*)&Bh[wn + j * 16 + ln][kt * 32 + q * 8];
#pragma unroll
            for (int i = 0; i < 4; i++)
#pragma unroll
                for (int j = 0; j < 4; j++)
                    acc[i][j] = __builtin_amdgcn_mfma_f32_16x16x32_bf16(avh[i], bvh[j], acc[i][j], 0, 0, 0);
            if (f32) {
                short8 avl[4], bvl[4];
#pragma unroll
                for (int i = 0; i < 4; i++) avl[i] = *(const short8*)&Al[wm + i * 16 + ln][kt * 32 + q * 8];
#pragma unroll
                for (int j = 0; j < 4; j++) bvl[j] = *(const short8*)&Bl[wn + j * 16 + ln][kt * 32 + q * 8];
#pragma unroll
                for (int i = 0; i < 4; i++)
#pragma unroll
                    for (int j = 0; j < 4; j++) {
                        acc[i][j] = __builtin_amdgcn_mfma_f32_16x16x32_bf16(avh[i], bvl[j], acc[i][j], 0, 0, 0);
                        acc[i][j] = __builtin_amdgcn_mfma_f32_16x16x32_bf16(avl[i], bvh[j], acc[i][j], 0, 0, 0);
                    }
            }
        }
        __syncthreads();
    }
    // C/D layout: col = lane&15, row = (lane>>4)*4 + reg
#pragma unroll
    for (int j = 0; j < 4; j++) {
        int col = bn + wn + j * 16 + ln;
        float bvv = ldf(bias, col, f32);
#pragma unroll
        for (int i = 0; i < 4; i++) {
#pragma unroll
            for (int r = 0; r < 4; r++) {
                int row = bm + wm + i * 16 + q * 4 + r;
                size_t idx = coff + (size_t)row * N + col;
                float v = acc[i][j][r] + bvv;
                if (f32) ((float*)outbase)[idx] = v;
                else     ((short*)outbase)[idx] = f2bf(v);
            }
        }
    }
}

// ---------------- persistent GRU recurrence ------------------------------------
// h exchange in k-blocked layout: plane[kb][b][8] shorts (kb = col/8, 128 kb, 64 b)
// -> every global h access is lane-contiguous 16B (coalesced), staged to LDS via
// global_load_lds in 4 double-buffered 64KB chunks. x_t staged (XOR-swizzled) to
// LDS BEFORE the producer barrier resolves; consumed while h chunk 0 is in flight.
// Coherence: relaxed polls + one acquire fence per step (reader), pre-barrier
// vmcnt(0) drain + one release fetch_add per step (writer).
#define NWG 64
__global__ __launch_bounds__(192, 1) void gru_rec(
    const void* __restrict__ inputs,   // (64,512,512)
    const void* __restrict__ Wx,       // (3072,512)
    const void* __restrict__ bx,       // 3072
    const void* __restrict__ Wh,       // (3072,1024)
    const void* __restrict__ bh,       // 3072
    short* __restrict__ hb,            // 4 planes of 65536 bf16 (ping hi/lo, pong hi/lo)
    unsigned* __restrict__ cnt,        // 512 step counters (zeroed)
    const unsigned* __restrict__ flag, // dtype flag (may be null -> bf16)
    void* __restrict__ hid)            // (64,512,1024) output 0
{
    const bool f32 = flag && (flag[0] != 0u);
    __shared__ short sbuf[2][32768];   // 2 x 64KB staging chunks (h dbuf / x)
    __shared__ float Px[3][64][17];
    __shared__ float Ph[3][64][17];
    __shared__ float hown[64][17];
    __shared__ float bxs[3][16], bhs[3][16];

    const int tid  = threadIdx.x;
    const int w    = blockIdx.x;
    const int g    = tid >> 6;         // 0..2 (gate / wave)
    const int lane = tid & 63;
    const int ln   = lane & 15, q = lane >> 4;

    // Wh / Wx B-fragments in registers: B[k][n]: n=lane&15, k=(lane>>4)*8+j
    const size_t whbase = (size_t)(g * 1024 + w * 16 + ln) * 1024;
    short8 wf[32];
#pragma unroll
    for (int kt = 0; kt < 32; kt++) wf[kt] = frag8(Wh, whbase + kt * 32 + q * 8, f32);

    const size_t wxbase = (size_t)(g * 1024 + w * 16 + ln) * 512;
    short8 wxf[16];
#pragma unroll
    for (int kt = 0; kt < 16; kt++) wxf[kt] = frag8(Wx, wxbase + kt * 32 + q * 8, f32);

    for (int e = tid; e < 1024; e += 192) hown[e >> 4][e & 15] = 0.f;
    if (tid < 48) {
        int gg = tid >> 4, jj = tid & 15;
        bxs[gg][jj] = ldf(bx, gg * 1024 + w * 16 + jj, f32);
        bhs[gg][jj] = ldf(bh, gg * 1024 + w * 16 + jj, f32);
    }
    __syncthreads();

    for (int t = 0; t < 512; t++) {
        const short* hsrc = hb + (size_t)((t & 1) ? 2 : 0) * 65536;
        short*       hdst = hb + (size_t)((t & 1) ? 0 : 2) * 65536;

        float4v ax[4], ah[4];
#pragma unroll
        for (int mt = 0; mt < 4; mt++) { ax[mt] = (float4v){0.f,0.f,0.f,0.f}; ah[mt] = (float4v){0.f,0.f,0.f,0.f}; }

        // ===== stage x_t -> sbuf[0]; layout [kb=lane][b] bytes kb*1024 + (b*16 ^ ((kb&7)<<4))
        // (XOR swizzle: conflict-free ds_write AND conflict-free frag ds_read).
        // Reads only `inputs` -> legal before the barrier; absorbs barrier skew.
#pragma unroll 8
        for (int r = 0; r < 22; r++) {
            int b = g + 3 * r;
            if (b < 64) {
                size_t gi = (size_t)b * 262144 + (size_t)t * 512 + (size_t)lane * 8;
                short8 v = frag8(inputs, gi, f32);
                *(short8*)((char*)sbuf[0] + lane * 1024 + ((b * 16) ^ ((lane & 7) << 4))) = v;
            }
        }
        __syncthreads();

        // ===== resolve producer barrier for h(t-1): relaxed polls, ONE acquire fence
        if (t && tid == 0) {
            while (__hip_atomic_load(&cnt[t - 1], __ATOMIC_RELAXED, __HIP_MEMORY_SCOPE_AGENT) < NWG)
                __builtin_amdgcn_s_sleep(2);
            __builtin_amdgcn_fence(__ATOMIC_ACQUIRE, "agent");
        }
        __syncthreads();

        // ===== h phase: 4 chunks of 64KB (hi half0, hi half1, lo half0, lo half1)
        // prefetch chunk 0 into sbuf[1], consume x meanwhile (covers DMA latency)
        for (int s = g; s < 64; s += 3)
            gll16(hsrc + s * 512 + lane * 8, &sbuf[1][s * 512]);

#pragma unroll
        for (int ktl = 0; ktl < 16; ktl++) {
            const int kb = ktl * 4 + q;
#pragma unroll
            for (int mt = 0; mt < 4; mt++) {
                short8 a = *(const short8*)((const char*)sbuf[0] +
                               kb * 1024 + (((mt * 16 + ln) * 16) ^ ((kb & 7) << 4)));
                ax[mt] = __builtin_amdgcn_mfma_f32_16x16x32_bf16(a, wxf[ktl], ax[mt], 0, 0, 0);
            }
        }
        __syncthreads();   // chunk 0 resident

#pragma unroll
        for (int c = 0; c < 4; c++) {
            if (c < 3) {   // prefetch chunk c+1 into the buffer consume just freed
                const short* src = hsrc + ((c + 1) >> 1) * 65536 + (size_t)((c + 1) & 1) * 32768;
                short* dst = sbuf[c & 1];
                for (int s = g; s < 64; s += 3)
                    gll16(src + s * 512 + lane * 8, dst + s * 512);
            }
            const short* bb = sbuf[(c + 1) & 1];
#pragma unroll
            for (int ktl = 0; ktl < 16; ktl++) {
                const int kb = ktl * 4 + q;
#pragma unroll
                for (int mt = 0; mt < 4; mt++) {
                    short8 a = *(const short8*)&bb[kb * 512 + (mt * 16 + ln) * 8];
                    ah[mt] = __builtin_amdgcn_mfma_f32_16x16x32_bf16(a, wf[(c & 1) * 16 + ktl], ah[mt], 0, 0, 0);
                }
            }
            __syncthreads();
        }

        // ===== accumulators -> LDS (C/D: col = lane&15, row = (lane>>4)*4 + reg)
#pragma unroll
        for (int mt = 0; mt < 4; mt++)
#pragma unroll
            for (int r = 0; r < 4; r++) {
                int row = mt * 16 + q * 4 + r;
                Px[g][row][ln] = ax[mt][r];
                Ph[g][row][ln] = ah[mt][r];
            }
        __syncthreads();

        // ===== gates + h update
        for (int e = tid; e < 1024; e += 192) {
            int b = e >> 4, jj = e & 15;
            float xr = Px[0][b][jj] + bxs[0][jj];
            float xu = Px[1][b][jj] + bxs[1][jj];
            float xn = Px[2][b][jj] + bxs[2][jj];
            float pr = Ph[0][b][jj] + bhs[0][jj];
            float pu = Ph[1][b][jj] + bhs[1][jj];
            float pn = Ph[2][b][jj] + bhs[2][jj];
            float rg = 1.f / (1.f + __expf(-(xr + pr)));
            float ug = 1.f / (1.f + __expf(-(xu + pu)));
            float ng = tanhf(xn + rg * pn);
            float hy = ug * hown[b][jj] + (1.f - ug) * ng;
            hown[b][jj] = hy;
            size_t hidx = ((size_t)b * 512 + t) * 1024 + w * 16 + jj;
            if (f32) ((float*)hid)[hidx] = hy;
            else     ((short*)hid)[hidx] = f2bf(hy);
        }
        __syncthreads();

        // ===== h out: blocked [kb][b][8], hi + lo planes, coalesced 16B stores
        for (int e = tid; e < 256; e += 192) {
            int b = e & 63, kbl = (e >> 6) & 1, pl = e >> 7;
            short8 v;
#pragma unroll
            for (int j = 0; j < 8; j++) {
                float hy = hown[b][kbl * 8 + j];
                short hh = f2bf(hy);
                v[j] = pl ? f2bf(hy - bf2f(hh)) : hh;
            }
            *(short8*)&hdst[(size_t)pl * 65536 + (size_t)(w * 2 + kbl) * 512 + b * 8] = v;
        }
        __syncthreads();   // pre-barrier waitcnt drains ALL waves' stores (fixes old race)

        if (tid == 0)
            __hip_atomic_fetch_add(&cnt[t], 1u, __ATOMIC_RELEASE, __HIP_MEMORY_SCOPE_AGENT);
    }
}

extern "C" void kernel_launch(void* const* d_in, const int* in_sizes, int n_in,
                              void* d_out, int out_size, void* d_ws, size_t ws_size,
                              hipStream_t stream)
{
    const void* inputs = d_in[0];
    const void* Wx     = d_in[1];
    const void* bx     = d_in[2];
    const void* Wh     = d_in[3];
    const void* bh     = d_in[4];
    const void* Wo     = d_in[5];
    const void* bo     = d_in[6];

    const size_t HID_ELEMS = (size_t)64 * 512 * 1024;   // 33,554,432

    short* hb; unsigned* cnt; unsigned* flag;
    const bool use_ws = (d_ws != nullptr) && (ws_size >= (size_t)(4096 + 4 * 65536 * 2));
    if (use_ws) {
        cnt  = (unsigned*)d_ws;                  // 512 u32
        flag = cnt + 512;                        // 1 u32
        hb   = (short*)((char*)d_ws + 4096);     // 512 KiB, 16B-aligned
    } else {
        short* outh = (short*)d_out + HID_ELEMS;
        hb   = outh;
        cnt  = (unsigned*)(outh + 4 * 65536);
        flag = nullptr;
    }

    if (use_ws) detect_dtype<<<1, 64, 0, stream>>>((const unsigned short*)inputs, flag);
    init_scratch<<<1024, 256, 0, stream>>>(hb, cnt);
    gru_rec<<<NWG, 192, 0, stream>>>(inputs, Wx, bx, Wh, bh, hb, cnt, flag, d_out);
    // out = hiddens @ Wo^T + bo : (32768 x 1024) @ (1024 x 512)
    gemm_bt<<<dim3(256, 4), 256, 0, stream>>>(d_out, Wo, bo, d_out, HID_ELEMS, flag, 32768, 512, 1024);
}

// Round 3
// 14725.464 us; speedup vs baseline: 2.2491x; 1.0033x over previous
//
#include <hip/hip_runtime.h>
#include <hip/hip_bf16.h>

typedef __attribute__((ext_vector_type(8))) short short8;
typedef __attribute__((ext_vector_type(4))) float float4v;

__device__ __forceinline__ float bf2f(short b) {
    unsigned u = ((unsigned)(unsigned short)b) << 16;
    union { unsigned u; float f; } c; c.u = u; return c.f;
}
__device__ __forceinline__ short f2bf(float f) {
    union { float f; unsigned u; } c; c.f = f;
    unsigned r = 0x7FFFu + ((c.u >> 16) & 1u);
    return (short)((c.u + r) >> 16);
}
// dtype-dispatched scalar load (flag: false=bf16, true=fp32)
__device__ __forceinline__ float ldf(const void* p, size_t i, bool f32) {
    return f32 ? ((const float*)p)[i] : bf2f(((const short*)p)[i]);
}
// dtype-dispatched 8-element MFMA fragment load (rounds fp32 -> bf16)
__device__ __forceinline__ short8 frag8(const void* p, size_t i, bool f32) {
    short8 r;
    if (f32) {
        const float* q = (const float*)p + i;
#pragma unroll
        for (int j = 0; j < 8; j++) r[j] = f2bf(q[j]);
    } else {
        r = *(const short8*)((const short*)p + i);
    }
    return r;
}

// async global->LDS DMA, 16B per lane; LDS dest is wave-uniform base + lane*16
__device__ __forceinline__ void gll16(const short* gp, short* lp) {
    __builtin_amdgcn_global_load_lds(
        (__attribute__((address_space(1))) void*)gp,
        (__attribute__((address_space(3))) void*)lp, 16, 0, 0);
}

// ---------------- dtype detector: 0 = bf16, 1 = fp32 ----------------
__global__ void detect_dtype(const unsigned short* __restrict__ in, unsigned* __restrict__ flag)
{
    int t = threadIdx.x;  // 64 threads
    int sane = 0;
    for (int i = t; i < 256; i += 64) {
        unsigned e = (in[i] >> 7) & 0xFF;
        sane += (e >= 0x70 && e <= 0x8A) ? 1 : 0;
    }
#pragma unroll
    for (int o = 32; o > 0; o >>= 1) sane += __shfl_down(sane, o);
    if (t == 0) *flag = (sane >= 200) ? 0u : 1u;
}

// ---------------- init scratch (h ping-pong hi/lo planes + flags) ----------------
__global__ void init_scratch(short* __restrict__ hb, unsigned* __restrict__ cnt)
{
    int i = blockIdx.x * 256 + threadIdx.x;
    if (i < 4 * 65536) hb[i] = 0;
    if (i < 512) cnt[i] = 0;
}

// ---------------- C = A @ B^T + bias, bf16 MFMA, optional fp32 hi/lo split --------
__global__ __launch_bounds__(256, 1) void gemm_bt(
    const void* __restrict__ A, const void* __restrict__ B,
    const void* __restrict__ bias, void* __restrict__ outbase, size_t coff,
    const unsigned* __restrict__ flag, int M, int N, int K)
{
    const bool f32 = flag && (flag[0] != 0u);
    __shared__ short Ah[128][72], Bh[128][72];
    __shared__ short Al[128][72], Bl[128][72];
    const int tid  = threadIdx.x;
    const int wid  = tid >> 6;
    const int lane = tid & 63;
    const int ln = lane & 15, q = lane >> 4;
    const int bm = blockIdx.x * 128, bn = blockIdx.y * 128;
    const int wm = (wid & 1) * 64, wn = (wid >> 1) * 64;

    float4v acc[4][4];
#pragma unroll
    for (int i = 0; i < 4; i++)
#pragma unroll
        for (int j = 0; j < 4; j++) acc[i][j] = (float4v){0.f, 0.f, 0.f, 0.f};

    for (int k0 = 0; k0 < K; k0 += 64) {
#pragma unroll
        for (int c = 0; c < 4; c++) {
            int chunk = tid + c * 256;
            int row = chunk >> 3;
            int kq  = (chunk & 7) * 8;
            size_t ga = (size_t)(bm + row) * K + k0 + kq;
            size_t gb = (size_t)(bn + row) * K + k0 + kq;
            if (f32) {
                const float* Af = (const float*)A;
                const float* Bf = (const float*)B;
#pragma unroll
                for (int j = 0; j < 8; j++) {
                    float av = Af[ga + j], bv = Bf[gb + j];
                    short ah = f2bf(av), bh = f2bf(bv);
                    Ah[row][kq + j] = ah; Al[row][kq + j] = f2bf(av - bf2f(ah));
                    Bh[row][kq + j] = bh; Bl[row][kq + j] = f2bf(bv - bf2f(bh));
                }
            } else {
                *(short8*)&Ah[row][kq] = *(const short8*)((const short*)A + ga);
                *(short8*)&Bh[row][kq] = *(const short8*)((const short*)B + gb);
            }
        }
        __syncthreads();
#pragma unroll
        for (int kt = 0; kt < 2; kt++) {
            short8 avh[4], bvh[4];
#pragma unroll
            for (int i = 0; i < 4; i++) avh[i] = *(const short8*)&Ah[wm + i * 16 + ln][kt * 32 + q * 8];
#pragma unroll
            for (int j = 0; j < 4; j++) bvh[j] = *(const short8*)&Bh[wn + j * 16 + ln][kt * 32 + q * 8];
#pragma unroll
            for (int i = 0; i < 4; i++)
#pragma unroll
                for (int j = 0; j < 4; j++)
                    acc[i][j] = __builtin_amdgcn_mfma_f32_16x16x32_bf16(avh[i], bvh[j], acc[i][j], 0, 0, 0);
            if (f32) {
                short8 avl[4], bvl[4];
#pragma unroll
                for (int i = 0; i < 4; i++) avl[i] = *(const short8*)&Al[wm + i * 16 + ln][kt * 32 + q * 8];
#pragma unroll
                for (int j = 0; j < 4; j++) bvl[j] = *(const short8*)&Bl[wn + j * 16 + ln][kt * 32 + q * 8];
#pragma unroll
                for (int i = 0; i < 4; i++)
#pragma unroll
                    for (int j = 0; j < 4; j++) {
                        acc[i][j] = __builtin_amdgcn_mfma_f32_16x16x32_bf16(avh[i], bvl[j], acc[i][j], 0, 0, 0);
                        acc[i][j] = __builtin_amdgcn_mfma_f32_16x16x32_bf16(avl[i], bvh[j], acc[i][j], 0, 0, 0);
                    }
            }
        }
        __syncthreads();
    }
    // C/D layout: col = lane&15, row = (lane>>4)*4 + reg
#pragma unroll
    for (int j = 0; j < 4; j++) {
        int col = bn + wn + j * 16 + ln;
        float bvv = ldf(bias, col, f32);
#pragma unroll
        for (int i = 0; i < 4; i++) {
#pragma unroll
            for (int r = 0; r < 4; r++) {
                int row = bm + wm + i * 16 + q * 4 + r;
                size_t idx = coff + (size_t)row * N + col;
                float v = acc[i][j][r] + bvv;
                if (f32) ((float*)outbase)[idx] = v;
                else     ((short*)outbase)[idx] = f2bf(v);
            }
        }
    }
}

// ---------------- persistent GRU recurrence ------------------------------------
// h exchange in k-blocked layout: plane[kb][b][8] shorts (kb = col/8, 128 kb, 64 b)
// -> every global h access is lane-contiguous 16B (coalesced), staged to LDS via
// global_load_lds in 4 double-buffered 64KB chunks. x_t staged (XOR-swizzled) to
// LDS BEFORE the producer barrier resolves; consumed while h chunk 0 is in flight.
// Step barrier: per-WG padded release-STORE flags (no same-address RMW chain) +
// 64-lane parallel relaxed poll + one acquire fence per step.
#define NWG 64
__global__ __launch_bounds__(192, 1) void gru_rec(
    const void* __restrict__ inputs,   // (64,512,512)
    const void* __restrict__ Wx,       // (3072,512)
    const void* __restrict__ bx,       // 3072
    const void* __restrict__ Wh,       // (3072,1024)
    const void* __restrict__ bh,       // 3072
    short* __restrict__ hb,            // 4 planes of 65536 bf16 (ping hi/lo, pong hi/lo)
    unsigned* __restrict__ cnt,        // 512 u32: flags[2][64] padded x4 (zeroed)
    const unsigned* __restrict__ flag, // dtype flag (may be null -> bf16)
    void* __restrict__ hid)            // (64,512,1024) output 0
{
    const bool f32 = flag && (flag[0] != 0u);
    __shared__ short sbuf[2][32768];   // 2 x 64KB staging chunks (h dbuf / x)
    __shared__ float Px[3][64][17];
    __shared__ float Ph[3][64][17];
    __shared__ float hown[64][17];
    __shared__ float bxs[3][16], bhs[3][16];

    const int tid  = threadIdx.x;
    const int w    = blockIdx.x;
    const int g    = tid >> 6;         // 0..2 (gate / wave)
    const int lane = tid & 63;
    const int ln   = lane & 15, q = lane >> 4;

    // Wh / Wx B-fragments in registers: B[k][n]: n=lane&15, k=(lane>>4)*8+j
    const size_t whbase = (size_t)(g * 1024 + w * 16 + ln) * 1024;
    short8 wf[32];
#pragma unroll
    for (int kt = 0; kt < 32; kt++) wf[kt] = frag8(Wh, whbase + kt * 32 + q * 8, f32);

    const size_t wxbase = (size_t)(g * 1024 + w * 16 + ln) * 512;
    short8 wxf[16];
#pragma unroll
    for (int kt = 0; kt < 16; kt++) wxf[kt] = frag8(Wx, wxbase + kt * 32 + q * 8, f32);

    for (int e = tid; e < 1024; e += 192) hown[e >> 4][e & 15] = 0.f;
    if (tid < 48) {
        int gg = tid >> 4, jj = tid & 15;
        bxs[gg][jj] = ldf(bx, gg * 1024 + w * 16 + jj, f32);
        bhs[gg][jj] = ldf(bh, gg * 1024 + w * 16 + jj, f32);
    }
    __syncthreads();

    for (int t = 0; t < 512; t++) {
        const short* hsrc = hb + (size_t)((t & 1) ? 2 : 0) * 65536;
        short*       hdst = hb + (size_t)((t & 1) ? 0 : 2) * 65536;

        float4v ax[4], ah[4];
#pragma unroll
        for (int mt = 0; mt < 4; mt++) { ax[mt] = (float4v){0.f,0.f,0.f,0.f}; ah[mt] = (float4v){0.f,0.f,0.f,0.f}; }

        // ===== stage x_t -> sbuf[0]; layout [kb=lane][b] bytes kb*1024 + (b*16 ^ ((kb&7)<<4))
        // (XOR swizzle: conflict-free ds_write AND conflict-free frag ds_read).
        // Reads only `inputs` -> legal before the barrier; absorbs barrier skew.
#pragma unroll 8
        for (int r = 0; r < 22; r++) {
            int b = g + 3 * r;
            if (b < 64) {
                size_t gi = (size_t)b * 262144 + (size_t)t * 512 + (size_t)lane * 8;
                short8 v = frag8(inputs, gi, f32);
                *(short8*)((char*)sbuf[0] + lane * 1024 + ((b * 16) ^ ((lane & 7) << 4))) = v;
            }
        }
        __syncthreads();

        // ===== resolve producer flags for h(t-1): 64-lane parallel relaxed poll,
        // then ONE acquire fence. Flag value == step count (monotone, 2-phase slots).
        if (t) {
            if (tid < 64) {
                const unsigned* fp = &cnt[(((t - 1) & 1) * 64 + tid) * 4];
                while (__hip_atomic_load(fp, __ATOMIC_RELAXED, __HIP_MEMORY_SCOPE_AGENT) < (unsigned)t)
                    __builtin_amdgcn_s_sleep(2);
            }
            if (tid == 0) __builtin_amdgcn_fence(__ATOMIC_ACQUIRE, "agent");
        }
        __syncthreads();

        // ===== h phase: 4 chunks of 64KB (hi half0, hi half1, lo half0, lo half1)
        // prefetch chunk 0 into sbuf[1], consume x meanwhile (covers DMA latency)
        for (int s = g; s < 64; s += 3)
            gll16(hsrc + s * 512 + lane * 8, &sbuf[1][s * 512]);

#pragma unroll
        for (int ktl = 0; ktl < 16; ktl++) {
            const int kb = ktl * 4 + q;
#pragma unroll
            for (int mt = 0; mt < 4; mt++) {
                short8 a = *(const short8*)((const char*)sbuf[0] +
                               kb * 1024 + (((mt * 16 + ln) * 16) ^ ((kb & 7) << 4)));
                ax[mt] = __builtin_amdgcn_mfma_f32_16x16x32_bf16(a, wxf[ktl], ax[mt], 0, 0, 0);
            }
        }
        __syncthreads();   // chunk 0 resident

#pragma unroll
        for (int c = 0; c < 4; c++) {
            if (c < 3) {   // prefetch chunk c+1 into the buffer consume just freed
                const short* src = hsrc + ((c + 1) >> 1) * 65536 + (size_t)((c + 1) & 1) * 32768;
                short* dst = sbuf[c & 1];
                for (int s = g; s < 64; s += 3)
                    gll16(src + s * 512 + lane * 8, dst + s * 512);
            }
            const short* bb = sbuf[(c + 1) & 1];
#pragma unroll
            for (int ktl = 0; ktl < 16; ktl++) {
                const int kb = ktl * 4 + q;
#pragma unroll
                for (int mt = 0; mt < 4; mt++) {
                    short8 a = *(const short8*)&bb[kb * 512 + (mt * 16 + ln) * 8];
                    ah[mt] = __builtin_amdgcn_mfma_f32_16x16x32_bf16(a, wf[(c & 1) * 16 + ktl], ah[mt], 0, 0, 0);
                }
            }
            __syncthreads();
        }

        // ===== accumulators -> LDS (C/D: col = lane&15, row = (lane>>4)*4 + reg)
#pragma unroll
        for (int mt = 0; mt < 4; mt++)
#pragma unroll
            for (int r = 0; r < 4; r++) {
                int row = mt * 16 + q * 4 + r;
                Px[g][row][ln] = ax[mt][r];
                Ph[g][row][ln] = ah[mt][r];
            }
        __syncthreads();

        // ===== gates + h update
        for (int e = tid; e < 1024; e += 192) {
            int b = e >> 4, jj = e & 15;
            float xr = Px[0][b][jj] + bxs[0][jj];
            float xu = Px[1][b][jj] + bxs[1][jj];
            float xn = Px[2][b][jj] + bxs[2][jj];
            float pr = Ph[0][b][jj] + bhs[0][jj];
            float pu = Ph[1][b][jj] + bhs[1][jj];
            float pn = Ph[2][b][jj] + bhs[2][jj];
            float rg = 1.f / (1.f + __expf(-(xr + pr)));
            float ug = 1.f / (1.f + __expf(-(xu + pu)));
            float ng = tanhf(xn + rg * pn);
            float hy = ug * hown[b][jj] + (1.f - ug) * ng;
            hown[b][jj] = hy;
            size_t hidx = ((size_t)b * 512 + t) * 1024 + w * 16 + jj;
            if (f32) ((float*)hid)[hidx] = hy;
            else     ((short*)hid)[hidx] = f2bf(hy);
        }
        __syncthreads();

        // ===== h out: blocked [kb][b][8], hi + lo planes, coalesced 16B stores
        for (int e = tid; e < 256; e += 192) {
            int b = e & 63, kbl = (e >> 6) & 1, pl = e >> 7;
            short8 v;
#pragma unroll
            for (int j = 0; j < 8; j++) {
                float hy = hown[b][kbl * 8 + j];
                short hh = f2bf(hy);
                v[j] = pl ? f2bf(hy - bf2f(hh)) : hh;
            }
            *(short8*)&hdst[(size_t)pl * 65536 + (size_t)(w * 2 + kbl) * 512 + b * 8] = v;
        }
        __syncthreads();   // pre-barrier waitcnt drains ALL waves' stores

        // ===== arrive: release fence + relaxed store to OWN padded flag slot
        if (tid == 0) {
            __builtin_amdgcn_fence(__ATOMIC_RELEASE, "agent");
            __hip_atomic_store(&cnt[((t & 1) * 64 + w) * 4], (unsigned)(t + 1),
                               __ATOMIC_RELAXED, __HIP_MEMORY_SCOPE_AGENT);
        }
    }
}

extern "C" void kernel_launch(void* const* d_in, const int* in_sizes, int n_in,
                              void* d_out, int out_size, void* d_ws, size_t ws_size,
                              hipStream_t stream)
{
    const void* inputs = d_in[0];
    const void* Wx     = d_in[1];
    const void* bx     = d_in[2];
    const void* Wh     = d_in[3];
    const void* bh     = d_in[4];
    const void* Wo     = d_in[5];
    const void* bo     = d_in[6];

    const size_t HID_ELEMS = (size_t)64 * 512 * 1024;   // 33,554,432

    short* hb; unsigned* cnt; unsigned* flag;
    const bool use_ws = (d_ws != nullptr) && (ws_size >= (size_t)(4096 + 4 * 65536 * 2));
    if (use_ws) {
        cnt  = (unsigned*)d_ws;                  // 512 u32: flags[2][64] x4 pad
        flag = cnt + 512;                        // 1 u32
        hb   = (short*)((char*)d_ws + 4096);     // 512 KiB, 16B-aligned
    } else {
        short* outh = (short*)d_out + HID_ELEMS;
        hb   = outh;
        cnt  = (unsigned*)(outh + 4 * 65536);
        flag = nullptr;
    }

    if (use_ws) detect_dtype<<<1, 64, 0, stream>>>((const unsigned short*)inputs, flag);
    init_scratch<<<1024, 256, 0, stream>>>(hb, cnt);
    gru_rec<<<NWG, 192, 0, stream>>>(inputs, Wx, bx, Wh, bh, hb, cnt, flag, d_out);
    // out = hiddens @ Wo^T + bo : (32768 x 1024) @ (1024 x 512)
    gemm_bt<<<dim3(256, 4), 256, 0, stream>>>(d_out, Wo, bo, d_out, HID_ELEMS, flag, 32768, 512, 1024);
}